// Round 9
// baseline (272.410 us; speedup 1.0000x reference)
//
#include <hip/hip_runtime.h>
#include <math.h>

// Problem constants: B=2, S=2048, U=1024, H=16, DK=64
#define B_NUM 2
#define S_LEN 2048
#define U_DIM 1024
#define H_NUM 16
#define DK 64
#define M_TOT (B_NUM * S_LEN)   // 4096

typedef __attribute__((ext_vector_type(8))) short bf8;   // 8 bf16 (MFMA A/B frag)
typedef __attribute__((ext_vector_type(4))) float f4;    // MFMA C/D frag

// float -> bf16 (round to nearest even), raw ushort bits
__device__ __forceinline__ unsigned short f2bf(float f) {
    union { float f; unsigned int u; } x; x.f = f;
    unsigned int r = x.u + 0x7fffu + ((x.u >> 16) & 1u);
    return (unsigned short)(r >> 16);
}

// pack two fp32 (raw bits) -> two bf16 (round-half-up), elem0 in low half
__device__ __forceinline__ unsigned int pkbf(unsigned int u0, unsigned int u1) {
    return __builtin_amdgcn_perm(u1 + 0x8000u, u0 + 0x8000u, 0x07060302u);
}

// async global->LDS, 16 B per lane; LDS dest = wave-uniform base + lane*16
__device__ __forceinline__ void gl2lds16(const void* g, void* l) {
    __builtin_amdgcn_global_load_lds(
        (const __attribute__((address_space(1))) unsigned int*)g,
        (__attribute__((address_space(3))) unsigned int*)l, 16, 0, 0);
}

// ---------------------------------------------------------------------------
// Weight fp32 -> bf16 conversion (4 x 1M elements only; activations are
// converted inside the QKV GEMM staging now).
// ---------------------------------------------------------------------------
struct CvtArgs {
    const float* src[4];
    unsigned short* dst[4];
};

__global__ __launch_bounds__(256) void convert_w(CvtArgs a)
{
    const int seg = blockIdx.y;
    const int i = (blockIdx.x * 256 + threadIdx.x) * 8;
    const float* s = a.src[seg] + i;
    float4 v0 = *(const float4*)s;
    float4 v1 = *(const float4*)(s + 4);
    unsigned int p0 = (unsigned)f2bf(v0.x) | ((unsigned)f2bf(v0.y) << 16);
    unsigned int p1 = (unsigned)f2bf(v0.z) | ((unsigned)f2bf(v0.w) << 16);
    unsigned int p2 = (unsigned)f2bf(v1.x) | ((unsigned)f2bf(v1.y) << 16);
    unsigned int p3 = (unsigned)f2bf(v1.z) | ((unsigned)f2bf(v1.w) << 16);
    uint4 o = {p0, p1, p2, p3};
    *(uint4*)(a.dst[seg] + i) = o;
}

// ---------------------------------------------------------------------------
// Fused QKV GEMM: A is fp32 (converted in-register during staging -> no
// separate convert pass); W is pre-converted bf16. Register-prefetch + LDS
// double buffer (R7-validated). z==2 (V) writes V^T DIRECTLY via an LDS
// retile in the epilogue (no transpose kernel): two 64-col phases through
// a TT[64][136] view of the freed As/Bs space (pad 8 -> banks spread).
// ---------------------------------------------------------------------------
struct QkvArgs {
    const float* A[3];
    const unsigned short* W[3];
    const float* bias[3];
    unsigned short* C[3];     // C[2] = VT base
    float scale[3];
};

__global__ __launch_bounds__(256, 3) void gemm_qkv(QkvArgs args)
{
    // unified LDS: As = lds[0][buf], Bs = lds[1][buf]; epilogue reuses flat.
    __shared__ __align__(16) unsigned short lds[2][2][128][32];

    const int z = blockIdx.z;
    const float* __restrict__ A = args.A[z];
    const unsigned short* __restrict__ W = args.W[z];
    const float* __restrict__ bias = args.bias[z];
    const float scale = args.scale[z];

    const int tid = threadIdx.x;
    const int w = tid >> 6, lane = tid & 63;
    const int quad = lane >> 4, cid = lane & 15;
    const int wy = w >> 1, wx = w & 1;
    const int m0 = blockIdx.y * 128, n0 = blockIdx.x * 128;

    const int row_s = tid >> 1;                  // 0..127
    const int sp = tid & 1;                      // 16-elem half
    const int rr = (row_s >> 2) & 3;
    const int p0 = (2 * sp + rr) & 3;            // phys 16B slot of seg 2sp
    const int p1 = (2 * sp + 1 + rr) & 3;

    const float* gA = A + (size_t)(m0 + row_s) * U_DIM + 16 * sp;
    const unsigned short* gB = W + (size_t)(n0 + row_s) * U_DIM + 16 * sp;

    uint4 fa0, fa1, fa2, fa3, b0, b1;   // named regs (R4 lesson: no arrays)
#define GPF(k0_) do {                                       \
        const unsigned int* ap_ = (const unsigned int*)(gA + (k0_)); \
        fa0 = *(const uint4*)(ap_);                         \
        fa1 = *(const uint4*)(ap_ + 4);                     \
        fa2 = *(const uint4*)(ap_ + 8);                     \
        fa3 = *(const uint4*)(ap_ + 12);                    \
        b0 = *(const uint4*)(gB + (k0_));                   \
        b1 = *(const uint4*)(gB + (k0_) + 8);               \
    } while (0)

#define STAGE(buf_) do {                                    \
        uint4 A0, A1;                                       \
        A0.x = pkbf(fa0.x, fa0.y); A0.y = pkbf(fa0.z, fa0.w); \
        A0.z = pkbf(fa1.x, fa1.y); A0.w = pkbf(fa1.z, fa1.w); \
        A1.x = pkbf(fa2.x, fa2.y); A1.y = pkbf(fa2.z, fa2.w); \
        A1.z = pkbf(fa3.x, fa3.y); A1.w = pkbf(fa3.z, fa3.w); \
        *(uint4*)&lds[0][buf_][row_s][p0 * 8] = A0;         \
        *(uint4*)&lds[0][buf_][row_s][p1 * 8] = A1;         \
        *(uint4*)&lds[1][buf_][row_s][p0 * 8] = b0;         \
        *(uint4*)&lds[1][buf_][row_s][p1 * 8] = b1;         \
    } while (0)

    f4 acc[4][4] = {};

    GPF(0);
    STAGE(0);
    GPF(32);
    __syncthreads();

#pragma unroll 2
    for (int k0 = 0; k0 < U_DIM; k0 += 32) {
        const int cur = (k0 >> 5) & 1;
        if (k0 + 32 < U_DIM) {
            STAGE(cur ^ 1);
            if (k0 + 64 < U_DIM) GPF(k0 + 64);   // in flight across compute
        }

        bf8 af[4], bfr[4];
#pragma unroll
        for (int mt = 0; mt < 4; ++mt) {
            int row = wy * 64 + mt * 16 + cid;
            int seg = (quad + (row >> 2)) & 3;
            af[mt] = *(const bf8*)&lds[0][cur][row][seg * 8];
        }
#pragma unroll
        for (int nt = 0; nt < 4; ++nt) {
            int row = wx * 64 + nt * 16 + cid;
            int seg = (quad + (row >> 2)) & 3;
            bfr[nt] = *(const bf8*)&lds[1][cur][row][seg * 8];
        }
#pragma unroll
        for (int mt = 0; mt < 4; ++mt)
#pragma unroll
            for (int nt = 0; nt < 4; ++nt)
                acc[mt][nt] = __builtin_amdgcn_mfma_f32_16x16x32_bf16(
                    af[mt], bfr[nt], acc[mt][nt], 0, 0, 0);
        __syncthreads();
    }
#undef GPF
#undef STAGE

    if (z < 2) {
        // ---- row-major bf16 store (Q scaled by 0.125) ----
        unsigned short* C = args.C[z];
#pragma unroll
        for (int nt = 0; nt < 4; ++nt) {
            int col = n0 + wx * 64 + nt * 16 + cid;
            float bv = bias[col];
#pragma unroll
            for (int mt = 0; mt < 4; ++mt) {
                int rowb = m0 + wy * 64 + mt * 16 + quad * 4;
#pragma unroll
                for (int i = 0; i < 4; ++i)
                    C[(size_t)(rowb + i) * U_DIM + col] =
                        f2bf((acc[mt][nt][i] + bv) * scale);
            }
        }
    } else {
        // ---- V: write V^T directly. VT[((b*H+h)*64+d)*S + s].
        // Two phases over 64-col halves through TT[64][136] (17408 B <= 32K).
        unsigned short* VT = args.C[2];
        unsigned short* flat = &lds[0][0][0][0];
        const int bb = m0 >> 11;               // batch (2048 rows each)
        const int sbase = m0 & (S_LEN - 1);
        const int d_r = tid >> 2;              // 0..63 (read phase)
        const int qq = tid & 3;
#pragma unroll
        for (int p = 0; p < 2; ++p) {
            if (wx == p) {
#pragma unroll
                for (int nt = 0; nt < 4; ++nt) {
                    int cl = nt * 16 + cid;                // 0..63 local col
                    float bv = bias[n0 + p * 64 + cl];
#pragma unroll
                    for (int mt = 0; mt < 4; ++mt)
#pragma unroll
                        for (int i = 0; i < 4; ++i) {
                            int r = wy * 64 + mt * 16 + quad * 4 + i;
                            flat[cl * 136 + r] = f2bf(acc[mt][nt][i] + bv);
                        }
                }
            }
            __syncthreads();
            {
                int h = (n0 >> 6) + p;
                unsigned short* dst = VT +
                    ((size_t)(bb * H_NUM + h) * DK + d_r) * S_LEN + sbase + qq * 32;
                const unsigned short* src = &flat[d_r * 136 + qq * 32];
                uint4 t0 = *(const uint4*)(src);
                uint4 t1 = *(const uint4*)(src + 8);
                uint4 t2 = *(const uint4*)(src + 16);
                uint4 t3 = *(const uint4*)(src + 24);
                *(uint4*)(dst)      = t0;
                *(uint4*)(dst + 8)  = t1;
                *(uint4*)(dst + 16) = t2;
                *(uint4*)(dst + 24) = t3;
            }
            __syncthreads();
        }
    }
}

// ---------------------------------------------------------------------------
// O-projection GEMM (A bf16, W bf16, fp32 out), BN=64 (512 blocks, 2/CU),
// register-prefetch + LDS double buffer. R8-validated.
// ---------------------------------------------------------------------------
__global__ __launch_bounds__(256, 4) void gemm_obf(
    const unsigned short* __restrict__ A, const unsigned short* __restrict__ W,
    const float* __restrict__ bias, float* __restrict__ C)
{
    constexpr int BN = 64, NT = 2;
    __shared__ __align__(16) unsigned short As[2][128][32];
    __shared__ __align__(16) unsigned short Bs[2][BN][32];

    const int tid = threadIdx.x;
    const int w = tid >> 6, lane = tid & 63;
    const int quad = lane >> 4, cid = lane & 15;
    const int wy = w >> 1, wx = w & 1;
    const int m0 = blockIdx.y * 128, n0 = blockIdx.x * BN;

    const int row_s = tid >> 1;
    const int sp = tid & 1;
    const int rr = (row_s >> 2) & 3;
    const int p0 = (2 * sp + rr) & 3;
    const int p1 = (2 * sp + 1 + rr) & 3;
    const unsigned short* gA = A + (size_t)(m0 + row_s) * U_DIM + 16 * sp;

    const int rowB = tid >> 2;
    const int sb = tid & 3;
    const int pb = (sb + ((rowB >> 2) & 3)) & 3;
    const unsigned short* gB = W + (size_t)(n0 + rowB) * U_DIM + 8 * sb;

    uint4 a0, a1, b0;
#define GPF(k0_) do {                                   \
        a0 = *(const uint4*)(gA + (k0_));               \
        a1 = *(const uint4*)(gA + (k0_) + 8);           \
        b0 = *(const uint4*)(gB + (k0_));               \
    } while (0)
#define STAGE(buf_) do {                                \
        *(uint4*)&As[buf_][row_s][p0 * 8] = a0;         \
        *(uint4*)&As[buf_][row_s][p1 * 8] = a1;         \
        *(uint4*)&Bs[buf_][rowB][pb * 8] = b0;          \
    } while (0)

    f4 acc[4][NT] = {};

    GPF(0);
    STAGE(0);
    GPF(32);
    __syncthreads();

#pragma unroll 2
    for (int k0 = 0; k0 < U_DIM; k0 += 32) {
        const int cur = (k0 >> 5) & 1;
        if (k0 + 32 < U_DIM) {
            STAGE(cur ^ 1);
            if (k0 + 64 < U_DIM) GPF(k0 + 64);
        }

        bf8 af[4], bfr[NT];
#pragma unroll
        for (int mt = 0; mt < 4; ++mt) {
            int row = wy * 64 + mt * 16 + cid;
            int seg = (quad + (row >> 2)) & 3;
            af[mt] = *(const bf8*)&As[cur][row][seg * 8];
        }
#pragma unroll
        for (int nt = 0; nt < NT; ++nt) {
            int row = wx * 32 + nt * 16 + cid;
            int seg = (quad + (row >> 2)) & 3;
            bfr[nt] = *(const bf8*)&Bs[cur][row][seg * 8];
        }
#pragma unroll
        for (int mt = 0; mt < 4; ++mt)
#pragma unroll
            for (int nt = 0; nt < NT; ++nt)
                acc[mt][nt] = __builtin_amdgcn_mfma_f32_16x16x32_bf16(
                    af[mt], bfr[nt], acc[mt][nt], 0, 0, 0);
        __syncthreads();
    }
#undef GPF
#undef STAGE

#pragma unroll
    for (int nt = 0; nt < NT; ++nt) {
        int col = n0 + wx * 32 + nt * 16 + cid;
        float bv = bias[col];
#pragma unroll
        for (int mt = 0; mt < 4; ++mt) {
            int rowb = m0 + wy * 64 + mt * 16 + quad * 4;
#pragma unroll
            for (int i = 0; i < 4; ++i)
                C[(size_t)(rowb + i) * U_DIM + col] = acc[mt][nt][i] + bv;
        }
    }
}

// ---------------------------------------------------------------------------
// MFMA flash attention — R7-exact (70 us validated): 64-row Q-tile, 128-key
// K-tile, register-staged pipeline, no-max softmax with deferred l-reduction.
// ---------------------------------------------------------------------------
__global__ __launch_bounds__(256, 3) void attn_mfma(
    const unsigned short* __restrict__ Q, const unsigned short* __restrict__ K,
    const unsigned short* __restrict__ VT, unsigned short* __restrict__ O)
{
    __shared__ __align__(16) unsigned short Ks[128][64];
    __shared__ __align__(16) unsigned short Vs[64][128];
    __shared__ __align__(16) unsigned short Ps[4][16][72];   // + Q staging alias

    const int qt = (int)gridDim.x - 1 - (int)blockIdx.x;  // heaviest first
    const int q0 = qt * 64;
    const int h = blockIdx.y, b = blockIdx.z;
    const int tid = threadIdx.x, w = tid >> 6, lane = tid & 63;
    const int quad = lane >> 4, cid = lane & 15;

#define KFRAG(r, s) (*(const bf8*)&Ks[r][(((s) ^ ((r) & 7)) * 8)])
#define VFRAG(r, s) (*(const bf8*)&Vs[r][(((((s) & 8) | (((s) ^ (r)) & 7))) * 8)])

    unsigned short (*QsA)[64] = (unsigned short (*)[64])&Ps[0][0][0];
    const int srow8 = lane >> 3;
    const int sw = ((lane & 7) ^ srow8) * 8;
    {
        const unsigned short* qg =
            Q + ((size_t)b * S_LEN + q0 + w * 16 + srow8) * U_DIM + h * DK + sw;
        gl2lds16(qg, &QsA[w * 16][0]);
        gl2lds16(qg + 8 * U_DIM, &QsA[w * 16 + 8][0]);
    }
    __syncthreads();
    const bf8 qfa = *(const bf8*)&QsA[w * 16 + cid][(((quad) ^ (cid & 7)) * 8)];
    const bf8 qfb = *(const bf8*)&QsA[w * 16 + cid][((((quad + 4)) ^ (cid & 7)) * 8)];

    const unsigned short* kgl =
        K + ((size_t)b * S_LEN + w * 32 + srow8) * U_DIM + h * DK + (lane & 7) * 8;
    const int vr0 = lane >> 4;
    const int s16 = lane & 15;
    const unsigned short* vgl =
        VT + ((size_t)(b * H_NUM + h) * DK + w * 16 + vr0) * S_LEN + s16 * 8;
    const int spE = (((s16 & 8) | ((s16 ^ vr0) & 7))) * 8;
    const int spO = (((s16 & 8) | ((s16 ^ (vr0 + 4)) & 7))) * 8;
    const int ksw = ((lane & 7) ^ srow8) * 8;

    uint4 kr0, kr1, kr2, kr3, vq0, vq1, vq2, vq3;
#define PREFETCH(kt_) do {                                                    \
        const unsigned short* kp_ = kgl + (size_t)(kt_) * 128 * U_DIM;        \
        kr0 = *(const uint4*)(kp_);                                           \
        kr1 = *(const uint4*)(kp_ + (size_t)8 * U_DIM);                       \
        kr2 = *(const uint4*)(kp_ + (size_t)16 * U_DIM);                      \
        kr3 = *(const uint4*)(kp_ + (size_t)24 * U_DIM);                      \
        const unsigned short* vp_ = vgl + (kt_) * 128;                        \
        vq0 = *(const uint4*)(vp_);                                           \
        vq1 = *(const uint4*)(vp_ + (size_t)4 * S_LEN);                       \
        vq2 = *(const uint4*)(vp_ + (size_t)8 * S_LEN);                       \
        vq3 = *(const uint4*)(vp_ + (size_t)12 * S_LEN);                      \
    } while (0)

    f4 o[4] = {};
    float l_i[4] = {0.0f, 0.0f, 0.0f, 0.0f};

    const int nkt = (qt >> 1) + 1;
    PREFETCH(0);

    for (int kt = 0; kt < nkt; ++kt) {
        __syncthreads();
        *(uint4*)&Ks[w * 32 + 0  + srow8][ksw] = kr0;
        *(uint4*)&Ks[w * 32 + 8  + srow8][ksw] = kr1;
        *(uint4*)&Ks[w * 32 + 16 + srow8][ksw] = kr2;
        *(uint4*)&Ks[w * 32 + 24 + srow8][ksw] = kr3;
        *(uint4*)&Vs[w * 16 + 0  + vr0][spE] = vq0;
        *(uint4*)&Vs[w * 16 + 4  + vr0][spO] = vq1;
        *(uint4*)&Vs[w * 16 + 8  + vr0][spE] = vq2;
        *(uint4*)&Vs[w * 16 + 12 + vr0][spO] = vq3;
        __syncthreads();
        if (kt + 1 < nkt) PREFETCH(kt + 1);

        f4 sc[8];
#pragma unroll
        for (int t = 0; t < 8; ++t) {
            int r = t * 16 + cid;
            f4 a = {};
            a = __builtin_amdgcn_mfma_f32_16x16x32_bf16(qfa, KFRAG(r, quad), a, 0, 0, 0);
            a = __builtin_amdgcn_mfma_f32_16x16x32_bf16(qfb, KFRAG(r, quad + 4), a, 0, 0, 0);
            sc[t] = a;
        }

        if (kt == nkt - 1) {
#pragma unroll
            for (int t = 0; t < 8; ++t) {
                int col = kt * 128 + t * 16 + cid;
#pragma unroll
                for (int i = 0; i < 4; ++i) {
                    int row = q0 + w * 16 + quad * 4 + i;
                    if (col > row) sc[t][i] = -1e30f;
                }
            }
        }

#pragma unroll
        for (int i = 0; i < 4; ++i) {
#pragma unroll
            for (int t = 0; t < 8; ++t) {
                float p = __expf(sc[t][i]);
                sc[t][i] = p;
                l_i[i] += p;
            }
        }

#pragma unroll
        for (int t = 0; t < 4; ++t)
#pragma unroll
            for (int i = 0; i < 4; ++i)
                Ps[w][quad * 4 + i][t * 16 + cid] = f2bf(sc[t][i]);
        {
            bf8 pA0 = *(const bf8*)&Ps[w][cid][quad * 8];
            bf8 pA1 = *(const bf8*)&Ps[w][cid][32 + quad * 8];
#pragma unroll
            for (int t = 0; t < 4; ++t) {
                int r = t * 16 + cid;
                o[t] = __builtin_amdgcn_mfma_f32_16x16x32_bf16(pA0, VFRAG(r, quad), o[t], 0, 0, 0);
                o[t] = __builtin_amdgcn_mfma_f32_16x16x32_bf16(pA1, VFRAG(r, 4 + quad), o[t], 0, 0, 0);
            }
        }
#pragma unroll
        for (int t = 0; t < 4; ++t)
#pragma unroll
            for (int i = 0; i < 4; ++i)
                Ps[w][quad * 4 + i][t * 16 + cid] = f2bf(sc[4 + t][i]);
        {
            bf8 pB0 = *(const bf8*)&Ps[w][cid][quad * 8];
            bf8 pB1 = *(const bf8*)&Ps[w][cid][32 + quad * 8];
#pragma unroll
            for (int t = 0; t < 4; ++t) {
                int r = t * 16 + cid;
                o[t] = __builtin_amdgcn_mfma_f32_16x16x32_bf16(pB0, VFRAG(r, 8 + quad), o[t], 0, 0, 0);
                o[t] = __builtin_amdgcn_mfma_f32_16x16x32_bf16(pB1, VFRAG(r, 12 + quad), o[t], 0, 0, 0);
            }
        }
    }
#undef PREFETCH
#undef KFRAG
#undef VFRAG

#pragma unroll
    for (int i = 0; i < 4; ++i) {
        float l = l_i[i];
        l += __shfl_xor(l, 1);
        l += __shfl_xor(l, 2);
        l += __shfl_xor(l, 4);
        l += __shfl_xor(l, 8);
        float inv = 1.0f / l;
        int rowg = q0 + w * 16 + quad * 4 + i;
        size_t rbase = ((size_t)b * S_LEN + rowg) * U_DIM + h * DK;
#pragma unroll
        for (int t = 0; t < 4; ++t)
            O[rbase + t * 16 + cid] = f2bf(o[t][i] * inv);
    }
}

// ---------------------------------------------------------------------------
// ws layout (bf16): wqb|wkb|wvb|wob (2MB ea) | qg|kg|vt|ao (8MB ea) = 40 MB.
// 4 kernels: convert_w -> gemm_qkv (fused cvt + V^T epilogue) -> attn -> obf.
// ---------------------------------------------------------------------------
extern "C" void kernel_launch(void* const* d_in, const int* in_sizes, int n_in,
                              void* d_out, int out_size, void* d_ws, size_t ws_size,
                              hipStream_t stream)
{
    const float* query = (const float*)d_in[0];
    const float* key   = (const float*)d_in[1];
    const float* value = (const float*)d_in[2];
    const float* Wq = (const float*)d_in[4];
    const float* bq = (const float*)d_in[5];
    const float* Wk = (const float*)d_in[6];
    const float* bk = (const float*)d_in[7];
    const float* Wv = (const float*)d_in[8];
    const float* bv = (const float*)d_in[9];
    const float* Wo = (const float*)d_in[10];
    const float* bo = (const float*)d_in[11];
    float* out = (float*)d_out;

    const size_t ACT = (size_t)M_TOT * U_DIM;
    const size_t WT  = (size_t)U_DIM * U_DIM;

    unsigned short* wqb = (unsigned short*)d_ws;
    unsigned short* wkb = wqb + WT;
    unsigned short* wvb = wkb + WT;
    unsigned short* wob = wvb + WT;
    unsigned short* qg  = wob + WT;
    unsigned short* kg  = qg + ACT;
    unsigned short* vt  = kg + ACT;
    unsigned short* ao  = vt + ACT;

    CvtArgs ca;
    ca.src[0] = Wq; ca.dst[0] = wqb;
    ca.src[1] = Wk; ca.dst[1] = wkb;
    ca.src[2] = Wv; ca.dst[2] = wvb;
    ca.src[3] = Wo; ca.dst[3] = wob;
    convert_w<<<dim3(WT / (256 * 8), 4), 256, 0, stream>>>(ca);

    QkvArgs ga;
    ga.A[0] = query; ga.W[0] = wqb; ga.bias[0] = bq; ga.C[0] = qg; ga.scale[0] = 0.125f;
    ga.A[1] = key;   ga.W[1] = wkb; ga.bias[1] = bk; ga.C[1] = kg; ga.scale[1] = 1.0f;
    ga.A[2] = value; ga.W[2] = wvb; ga.bias[2] = bv; ga.C[2] = vt; ga.scale[2] = 1.0f;
    gemm_qkv<<<dim3(U_DIM / 128, M_TOT / 128, 3), 256, 0, stream>>>(ga);

    attn_mfma<<<dim3(S_LEN / 64, H_NUM, B_NUM), 256, 0, stream>>>(qg, kg, vt, ao);

    gemm_obf<<<dim3(U_DIM / 64, M_TOT / 128), 256, 0, stream>>>(ao, wob, bo, out);
}